// Round 13
// baseline (48.008 us; speedup 1.0000x reference)
//
#include <hip/hip_runtime.h>
#include <math.h>

#define BB 8
#define NN 2000
#define CC 81
#define NCLS 80             // classes 1..80 (class 0 never valid)
#define MAXI 100
#define MCLS 128            // per-class member cap (mean ~25, sd ~5)
#define WCAP 128            // per-wave collect cap
#define KCAP 2048           // per-batch kept keys (kept <= valid <= 2000)

static constexpr float kMinConf = 0.7f;
static constexpr float kNmsThr  = 0.3f;

// ---------------- workspace layout (bytes) ----------------
// boxes : [0,      256000)   BN*4 f32 (refined, clipped)
// sc    : [256000, 320000)   BN f32   (raw max score)
// cls   : [320000, 384000)   BN i32   (argmax class; 0 if invalid)
// kslot : [384000, 386560)   8*80 i32  per-(batch,class) kept count (-1 = not ready)
// klist : [386624, 1041984)  8*80*128 u64 kept keys, fixed slots

// key = (score_bits << 32) | ~idx. Valid scores are positive floats so u32
// compare == float compare; key desc == (score desc, idx asc) == reference's
// stable descending argsort. idx = ~(u32)key. Keys unique (idx).
__device__ __forceinline__ unsigned long long mkey(float s, int i) {
    return ((unsigned long long)__float_as_uint(s) << 32) | (unsigned int)(~(unsigned int)i);
}

__device__ __forceinline__ bool iou_gt_thr(float4 a, float aarea, float4 t) {
    float iy1 = fmaxf(a.x, t.x), ix1 = fmaxf(a.y, t.y);
    float iy2 = fminf(a.z, t.z), ix2 = fminf(a.w, t.w);
    float inter = fmaxf(iy2 - iy1, 0.f) * fmaxf(ix2 - ix1, 0.f);
    float tarea = (t.z - t.x) * (t.w - t.y);
    float uni = fmaxf(aarea + tarea - inter, 1e-12f);
    return inter > kNmsThr * uni;
}

// ---- kA: wave-per-ROI argmax + box refine; zero out[]; kslot = -1 ----
__global__ void kA_refine(const float* __restrict__ rois,
                          const float* __restrict__ probs,
                          const float* __restrict__ deltas,
                          float* __restrict__ boxes,
                          float* __restrict__ sc,
                          int* __restrict__ cls,
                          int* __restrict__ kslot,
                          float* __restrict__ outz) {
    int gtid = blockIdx.x * blockDim.x + threadIdx.x;
    if (gtid < BB * MAXI * 6) outz[gtid] = 0.f;      // pre-zero output
    if (gtid < BB * NCLS) kslot[gtid] = -1;          // not-ready sentinel

    int wid = gtid >> 6;                // one wave per ROI
    int l = gtid & 63;

    const float* p = probs + (size_t)wid * CC;
    float v1 = p[l];                    // l < 64 < 81 always valid
    int   i1 = l;
    int   c2 = l + 64;
    float v2 = (c2 < CC) ? p[c2] : -1.0f;   // probs in [0,1)
    float bv; int bi;
    if (v2 > v1) { bv = v2; bi = c2; } else { bv = v1; bi = i1; }

    #pragma unroll
    for (int off = 32; off; off >>= 1) {
        float ov = __shfl_xor(bv, off);
        int   oi = __shfl_xor(bi, off);
        if (ov > bv || (ov == bv && oi < bi)) { bv = ov; bi = oi; }
    }

    if (l == 0) {
        const float4 dl = *(const float4*)(deltas + ((size_t)wid * CC + bi) * 4);
        float dy = dl.x * 0.1f, dx = dl.y * 0.1f, dh = dl.z * 0.2f, dw = dl.w * 0.2f;
        const float4 r = *(const float4*)(rois + (size_t)wid * 4);
        float y1 = r.x, x1 = r.y, y2 = r.z, x2 = r.w;
        float h = y2 - y1, w = x2 - x1;
        float cy = y1 + 0.5f * h + dy * h;
        float cx = x1 + 0.5f * w + dx * w;
        float h2 = h * expf(dh);
        float w2 = w * expf(dw);
        float oy1 = fminf(fmaxf(cy - 0.5f * h2, 0.f), 1.f);
        float ox1 = fminf(fmaxf(cx - 0.5f * w2, 0.f), 1.f);
        float oy2 = fminf(fmaxf(cy + 0.5f * h2, 0.f), 1.f);
        float ox2 = fminf(fmaxf(cx + 0.5f * w2, 0.f), 1.f);
        bool valid = (bi > 0) && (bv >= kMinConf);
        float4 bx; bx.x = oy1; bx.y = ox1; bx.z = oy2; bx.w = ox2;
        ((float4*)boxes)[wid] = bx;
        sc[wid] = bv;
        cls[wid] = valid ? bi : 0;      // cls==0 encodes "invalid"
    }
}

// ---- K2: blocks [0, 640) = per-(batch,class) NMS (R12-validated), publishing
// the slot count with an agent-scope RELEASE store (lane-0; vmcnt(0) covers the
// wave's klist stores — only wave 0 writes klist). Blocks [640, 648) = per-batch
// emit: spin on the 80 counts (relaxed agent loads vs -1 sentinel; final counts
// kept in LDS), one acquire fence, then R12-validated stage+hist+rank emit. ----
__global__ void __launch_bounds__(256) k2_nms_emit(
        const float* __restrict__ boxes,
        const float* __restrict__ sc,
        const int* __restrict__ cls,
        int* __restrict__ kslot,
        unsigned long long* __restrict__ klist,
        float* __restrict__ out) {
    const int blk = blockIdx.x;
    const int tid = threadIdx.x;
    const int wv = tid >> 6;
    const int l = tid & 63;

    // NMS-side LDS
    __shared__ unsigned long long wlist[4][WCAP];   // 4 KB
    __shared__ int wcnt[4];
    __shared__ unsigned long long mk[MCLS];         // 1 KB
    __shared__ float4 mbox[MCLS];                   // 2 KB
    // emit-side LDS
    __shared__ unsigned long long keys[KCAP];       // 16 KB
    __shared__ ulonglong2 cand2[256];               //  4 KB
    __shared__ int hist[256];
    __shared__ int sbase[NCLS], scnt[NCLS];
    __shared__ int Tsh, tbsh, candn;
    unsigned long long* cand = (unsigned long long*)cand2;

    if (blk < BB * NCLS) {
        // ================= NMS block =================
        const int b = blk / NCLS;
        const int cidx = blk % NCLS;
        const int c = cidx + 1;         // classes 1..80

        const int* cl = cls + (size_t)b * NN;
        const float* ssc = sc + (size_t)b * NN;
        const float4* bxs = (const float4*)boxes + (size_t)b * NN;

        // parallel collect: wave wv scans rows [wv*500, wv*500+500)
        {
            int cnt = 0;
            const int base_row = wv * 500;
            for (int ch = 0; ch < 8; ++ch) {
                int idx = ch * 64 + l;
                bool inq = idx < 500;
                int r = base_row + idx;
                int ci = inq ? cl[r] : 0;
                bool pred = (ci == c);
                unsigned long long mask = __ballot(pred);
                if (pred) {
                    int pos = cnt + __popcll(mask & ((1ull << l) - 1ull));
                    if (pos < WCAP) wlist[wv][pos] = mkey(ssc[r], r);
                }
                cnt += __popcll(mask);
            }
            if (l == 0) wcnt[wv] = (cnt > WCAP) ? WCAP : cnt;
        }
        __syncthreads();

        // merge wave lists into mk
        int b0 = wcnt[0], b1 = wcnt[1], b2 = wcnt[2], b3 = wcnt[3];
        int myofs = (wv > 0 ? b0 : 0) + (wv > 1 ? b1 : 0) + (wv > 2 ? b2 : 0);
        int myn = wcnt[wv];
        int cnt_all = b0 + b1 + b2 + b3;
        if (cnt_all > MCLS) cnt_all = MCLS;
        if (l < myn && myofs + l < MCLS) mk[myofs + l] = wlist[wv][l];
        if (64 + l < myn && myofs + 64 + l < MCLS) mk[myofs + 64 + l] = wlist[wv][64 + l];
        __syncthreads();

        if (wv != 0) return;
        if (cnt_all == 0) {
            if (l == 0)
                __hip_atomic_store(&kslot[b * NCLS + cidx], 0,
                                   __ATOMIC_RELEASE, __HIP_MEMORY_SCOPE_AGENT);
            return;
        }
        const int cnt = cnt_all;

        // in-wave stable rank sort by key desc
        {
            unsigned long long Ka = (l < cnt) ? mk[l] : 0ull;
            unsigned long long Kb = (64 + l < cnt) ? mk[64 + l] : 0ull;
            int ra = 0, rb = 0;
            for (int t = 0; t < cnt; ++t) {
                unsigned long long kt = mk[t];
                ra += (kt > Ka);
                rb += (kt > Kb);
            }
            if (l < cnt) mk[ra] = Ka;
            if (64 + l < cnt) mk[rb] = Kb;
        }
        for (int t = l; t < cnt; t += 64) {
            int i = (int)(~(unsigned int)mk[t]);
            mbox[t] = bxs[i];
        }

        // chunk 0: ballot fixpoint == greedy (validated exact)
        unsigned long long kept0 = 0ull, kept1 = 0ull;
        {
            bool act = (l < cnt);
            float4 a = mbox[act ? l : 0];
            float aarea = (a.z - a.x) * (a.w - a.y);
            unsigned long long colmask = 0ull;
            int tend = min(64, cnt);
            for (int t = 0; t < tend; ++t) {
                float4 tb = mbox[t];
                if (t < l && act && iou_gt_thr(a, aarea, tb)) colmask |= (1ull << t);
            }
            unsigned long long kept = __ballot(act);
            while (true) {
                bool alive = act && ((colmask & kept) == 0ull);
                unsigned long long k2m = __ballot(alive);
                if (k2m == kept) break;
                kept = k2m;
            }
            kept0 = kept;
        }
        if (cnt > 64) {
            int m = 64 + l;
            bool act = (m < cnt);
            float4 a = mbox[act ? m : 0];
            float aarea = (a.z - a.x) * (a.w - a.y);
            bool presup = false;
            for (int t = 0; t < 64; ++t) {
                if ((kept0 >> t) & 1ull) {
                    if (act && iou_gt_thr(a, aarea, mbox[t])) presup = true;
                }
            }
            unsigned long long colmask = 0ull;
            for (int t = 64; t < cnt; ++t) {
                float4 tb = mbox[t];
                if ((t - 64) < l && act && iou_gt_thr(a, aarea, tb)) colmask |= (1ull << (t - 64));
            }
            bool pre = act && !presup;
            unsigned long long kept = __ballot(pre);
            while (true) {
                bool alive = pre && ((colmask & kept) == 0ull);
                unsigned long long k2m = __ballot(alive);
                if (k2m == kept) break;
                kept = k2m;
            }
            kept1 = kept;
        }

        // fixed-slot write, then RELEASE-publish the count
        int nk0 = __popcll(kept0), nk1 = __popcll(kept1);
        unsigned long long* slot = klist + ((size_t)b * NCLS + cidx) * MCLS;
        if ((kept0 >> l) & 1ull)
            slot[__popcll(kept0 & ((1ull << l) - 1ull))] = mk[l];
        if (cnt > 64 && ((kept1 >> l) & 1ull))
            slot[nk0 + __popcll(kept1 & ((1ull << l) - 1ull))] = mk[64 + l];
        if (l == 0)
            __hip_atomic_store(&kslot[b * NCLS + cidx], nk0 + nk1,
                               __ATOMIC_RELEASE, __HIP_MEMORY_SCOPE_AGENT);
        return;
    }

    // ================= emit block (batch b) =================
    const int b = blk - BB * NCLS;

    // spin on the 80 slot counts (relaxed agent loads; -1 = not ready)
    {
        int myc = 0;
        while (true) {
            myc = (tid < NCLS)
                ? __hip_atomic_load(&kslot[b * NCLS + tid],
                                    __ATOMIC_RELAXED, __HIP_MEMORY_SCOPE_AGENT)
                : 0;
            if (__syncthreads_and(myc >= 0)) break;
        }
        if (tid < NCLS) scnt[tid] = myc;             // final counts -> LDS only
    }
    __threadfence();                                 // acquire (8 blocks total)
    if (tid < 256 && tid >= 0) hist[tid] = 0;
    if (tid == 0) candn = 0;
    __syncthreads();

    // wave 0: 80 counts -> exclusive prefix (from LDS, not global)
    if (wv == 0) {
        int ns0 = scnt[l];
        int ns1 = (l < NCLS - 64) ? scnt[64 + l] : 0;
        int incA = ns0, incB = ns1;
        #pragma unroll
        for (int off = 1; off < 64; off <<= 1) {
            int oa = __shfl_up(incA, off);
            int ob = __shfl_up(incB, off);
            if (l >= off) { incA += oa; incB += ob; }
        }
        int total0 = __shfl(incA, 63);
        int T = total0 + __shfl(incB, 63);
        sbase[l] = incA - ns0;
        if (l < NCLS - 64) sbase[64 + l] = total0 + incB - ns1;
        if (l == 0) Tsh = (T > KCAP) ? KCAP : T;
    }
    __syncthreads();
    const int T = Tsh;
    if (T == 0) return;                              // out pre-zeroed by kA

    // stage: all 80*128 entries, coalesced unconditional loads, predicated scatter
    const unsigned long long* kbase = klist + (size_t)b * NCLS * MCLS;
    for (int e = tid; e < NCLS * MCLS; e += 256) {
        unsigned long long v = kbase[e];
        int s = e >> 7, j = e & (MCLS - 1);
        if (j < scnt[s]) keys[sbase[s] + j] = v;
    }
    __syncthreads();

    // histogram on score bucket ((key>>47)&0xFF monotone: scores in [0.7,1))
    for (int t = tid; t < T; t += 256)
        atomicAdd(&hist[(int)((keys[t] >> 47) & 0xFF)], 1);
    __syncthreads();

    // wave 0: threshold bucket tb
    if (wv == 0) {
        int cum = 0, tb = 0, done = 0;
        for (int chunk = 3; chunk >= 0 && !done; --chunk) {
            int bkt = chunk * 64 + (63 - l);
            int s = hist[bkt];
            #pragma unroll
            for (int off = 1; off < 64; off <<= 1) {
                int o = __shfl_up(s, off);
                if (l >= off) s += o;
            }
            int chunktot = __shfl(s, 63);
            if (cum + chunktot >= MAXI) {
                unsigned long long m = __ballot(cum + s >= MAXI);
                int lane = __ffsll((long long)m) - 1;
                tb = chunk * 64 + (63 - lane);
                done = 1;
            } else {
                cum += chunktot;
            }
        }
        if (l == 0) tbsh = done ? tb : 0;
    }
    __syncthreads();
    const int tb = tbsh;

    // compact candidates (bucket >= tb)
    for (int t = tid; t < ((T + 255) & ~255); t += 256) {
        bool pr = (t < T) && ((int)((keys[t] >> 47) & 0xFF) >= tb);
        unsigned long long m = __ballot(pr);
        int nb = __popcll(m);
        int basew = 0;
        if (l == 0 && nb) basew = atomicAdd(&candn, nb);
        basew = __shfl(basew, 0);
        if (pr) {
            int pos = basew + __popcll(m & ((1ull << l) - 1ull));
            if (pos < 512) cand[pos] = keys[t];
        }
    }
    __syncthreads();
    const int nc = candn;
    if (tid == 0 && nc < 512) cand[nc] = 0ull;       // pad for pair read
    __syncthreads();

    if (nc <= 512) {
        const int np = (nc + 1) >> 1;
        for (int s = tid; s < nc; s += 256) {
            unsigned long long myk = cand[s];
            int r = 0;
            for (int t = 0; t < np; ++t) {
                ulonglong2 kv = cand2[t];
                r += (int)(kv.x > myk);
                r += (int)(kv.y > myk);
            }
            if (r < MAXI) {
                int i = (int)(~(unsigned int)myk);
                float4 bx = ((const float4*)boxes)[(size_t)b * NN + i];
                float* o = out + ((size_t)b * MAXI + r) * 6;
                o[0] = bx.x; o[1] = bx.y; o[2] = bx.z; o[3] = bx.w;
                o[4] = (float)cls[(size_t)b * NN + i];
                o[5] = __uint_as_float((unsigned int)(myk >> 32));
            }
        }
    } else {
        for (int s = tid; s < T; s += 256) {
            unsigned long long myk = keys[s];
            int r = 0;
            for (int t = 0; t < T; ++t) r += (int)(keys[t] > myk);
            if (r < MAXI) {
                int i = (int)(~(unsigned int)myk);
                float4 bx = ((const float4*)boxes)[(size_t)b * NN + i];
                float* o = out + ((size_t)b * MAXI + r) * 6;
                o[0] = bx.x; o[1] = bx.y; o[2] = bx.z; o[3] = bx.w;
                o[4] = (float)cls[(size_t)b * NN + i];
                o[5] = __uint_as_float((unsigned int)(myk >> 32));
            }
        }
    }
}

extern "C" void kernel_launch(void* const* d_in, const int* in_sizes, int n_in,
                              void* d_out, int out_size, void* d_ws, size_t ws_size,
                              hipStream_t stream) {
    const float* rois   = (const float*)d_in[0];
    const float* probs  = (const float*)d_in[1];
    const float* deltas = (const float*)d_in[2];
    float* outp = (float*)d_out;

    char* ws = (char*)d_ws;
    float* boxes = (float*)(ws + 0);
    float* sc    = (float*)(ws + 256000);
    int*   cls   = (int*)  (ws + 320000);
    int*   kslot = (int*)  (ws + 384000);
    unsigned long long* klist = (unsigned long long*)(ws + 386624);

    {
        int blocks = (BB * NN * 64) / 256;   // one wave per ROI, exact
        kA_refine<<<blocks, 256, 0, stream>>>(rois, probs, deltas, boxes, sc, cls, kslot, outp);
    }
    {
        k2_nms_emit<<<BB * NCLS + BB, 256, 0, stream>>>(boxes, sc, cls, kslot, klist, outp);
    }
}

// Round 14
// 29.093 us; speedup vs baseline: 1.6501x; 1.6501x over previous
//
#include <hip/hip_runtime.h>
#include <math.h>

#define BB 8
#define NN 2000
#define CC 81
#define NCLS 80             // classes 1..80 (class 0 never valid)
#define MAXI 100
#define MCLS 128            // per-class member cap (mean ~25, sd ~5)
#define WCAP 128            // per-wave collect cap

static constexpr float kMinConf = 0.7f;
static constexpr float kNmsThr  = 0.3f;

// ---------------- workspace layout (bytes) ----------------
// boxes : [0,      256000)   BN*4 f32 (refined, clipped)
// sc    : [256000, 320000)   BN f32   (raw max score)
// cls   : [320000, 384000)   BN i32   (argmax class; 0 if invalid)
// kflag : [384000, 448000)   BN i32   (1 = kept by NMS; zeroed by kA)

// key = (score_bits << 32) | ~idx. Valid scores are positive floats so u32
// compare == float compare; key desc == (score desc, idx asc) == reference's
// stable descending argsort. idx = ~(u32)key. Keys unique; key==0 = "absent".
__device__ __forceinline__ unsigned long long mkey(float s, int i) {
    return ((unsigned long long)__float_as_uint(s) << 32) | (unsigned int)(~(unsigned int)i);
}

__device__ __forceinline__ bool iou_gt_thr(float4 a, float aarea, float4 t) {
    float iy1 = fmaxf(a.x, t.x), ix1 = fmaxf(a.y, t.y);
    float iy2 = fminf(a.z, t.z), ix2 = fminf(a.w, t.w);
    float inter = fmaxf(iy2 - iy1, 0.f) * fmaxf(ix2 - ix1, 0.f);
    float tarea = (t.z - t.x) * (t.w - t.y);
    float uni = fmaxf(aarea + tarea - inter, 1e-12f);
    return inter > kNmsThr * uni;
}

// ---- kA: wave-per-ROI argmax + box refine; zero out[] and kflag[] ----
__global__ void kA_refine(const float* __restrict__ rois,
                          const float* __restrict__ probs,
                          const float* __restrict__ deltas,
                          float* __restrict__ boxes,
                          float* __restrict__ sc,
                          int* __restrict__ cls,
                          int* __restrict__ kflag,
                          float* __restrict__ outz) {
    int gtid = blockIdx.x * blockDim.x + threadIdx.x;
    if (gtid < BB * MAXI * 6) outz[gtid] = 0.f;      // pre-zero output
    if (gtid < BB * NN) kflag[gtid] = 0;             // zero kept flags

    int wid = gtid >> 6;                // one wave per ROI
    int l = gtid & 63;

    const float* p = probs + (size_t)wid * CC;
    float v1 = p[l];                    // l < 64 < 81 always valid
    int   i1 = l;
    int   c2 = l + 64;
    float v2 = (c2 < CC) ? p[c2] : -1.0f;   // probs in [0,1)
    float bv; int bi;
    if (v2 > v1) { bv = v2; bi = c2; } else { bv = v1; bi = i1; }

    #pragma unroll
    for (int off = 32; off; off >>= 1) {
        float ov = __shfl_xor(bv, off);
        int   oi = __shfl_xor(bi, off);
        if (ov > bv || (ov == bv && oi < bi)) { bv = ov; bi = oi; }
    }

    if (l == 0) {
        const float4 dl = *(const float4*)(deltas + ((size_t)wid * CC + bi) * 4);
        float dy = dl.x * 0.1f, dx = dl.y * 0.1f, dh = dl.z * 0.2f, dw = dl.w * 0.2f;
        const float4 r = *(const float4*)(rois + (size_t)wid * 4);
        float y1 = r.x, x1 = r.y, y2 = r.z, x2 = r.w;
        float h = y2 - y1, w = x2 - x1;
        float cy = y1 + 0.5f * h + dy * h;
        float cx = x1 + 0.5f * w + dx * w;
        float h2 = h * expf(dh);
        float w2 = w * expf(dw);
        float oy1 = fminf(fmaxf(cy - 0.5f * h2, 0.f), 1.f);
        float ox1 = fminf(fmaxf(cx - 0.5f * w2, 0.f), 1.f);
        float oy2 = fminf(fmaxf(cy + 0.5f * h2, 0.f), 1.f);
        float ox2 = fminf(fmaxf(cx + 0.5f * w2, 0.f), 1.f);
        bool valid = (bi > 0) && (bv >= kMinConf);
        float4 bx; bx.x = oy1; bx.y = ox1; bx.z = oy2; bx.w = ox2;
        ((float4*)boxes)[wid] = bx;
        sc[wid] = bv;
        cls[wid] = valid ? bi : 0;      // cls==0 encodes "invalid"
    }
}

// ---- kB: one 256-thread block per (batch,class) (R12-validated NMS core);
// output is now just plain kflag[row] = 1 stores for kept rows — no slots,
// no atomics, no publication. ----
__global__ void __launch_bounds__(256) kB_nms(
        const float* __restrict__ boxes,
        const float* __restrict__ sc,
        const int* __restrict__ cls,
        int* __restrict__ kflag) {
    const int p = blockIdx.x;
    const int b = p / NCLS;
    const int cidx = p % NCLS;
    const int c = cidx + 1;             // classes 1..80
    const int tid = threadIdx.x;
    const int wv = tid >> 6;
    const int l = tid & 63;

    __shared__ unsigned long long wlist[4][WCAP];   // 4 KB
    __shared__ int wcnt[4];
    __shared__ unsigned long long mk[MCLS];         // 1 KB
    __shared__ float4 mbox[MCLS];                   // 2 KB

    const int* cl = cls + (size_t)b * NN;
    const float* ssc = sc + (size_t)b * NN;
    const float4* bxs = (const float4*)boxes + (size_t)b * NN;

    // ---- parallel collect: wave wv scans rows [wv*500, wv*500+500) ----
    {
        int cnt = 0;
        const int base_row = wv * 500;
        for (int ch = 0; ch < 8; ++ch) {
            int idx = ch * 64 + l;                   // 0..511
            bool inq = idx < 500;
            int r = base_row + idx;
            int ci = inq ? cl[r] : 0;
            bool pred = (ci == c);
            unsigned long long mask = __ballot(pred);
            if (pred) {
                int pos = cnt + __popcll(mask & ((1ull << l) - 1ull));
                if (pos < WCAP) wlist[wv][pos] = mkey(ssc[r], r);
            }
            cnt += __popcll(mask);
        }
        if (l == 0) wcnt[wv] = (cnt > WCAP) ? WCAP : cnt;
    }
    __syncthreads();

    // merge wave lists into mk (order irrelevant; sort is total on unique keys)
    int b0 = wcnt[0], b1 = wcnt[1], b2 = wcnt[2], b3 = wcnt[3];
    int myofs = (wv > 0 ? b0 : 0) + (wv > 1 ? b1 : 0) + (wv > 2 ? b2 : 0);
    int myn = wcnt[wv];
    int cnt_all = b0 + b1 + b2 + b3;
    if (cnt_all > MCLS) cnt_all = MCLS;
    if (l < myn && myofs + l < MCLS) mk[myofs + l] = wlist[wv][l];
    if (64 + l < myn && myofs + 64 + l < MCLS) mk[myofs + 64 + l] = wlist[wv][64 + l];
    __syncthreads();

    if (wv != 0) return;                             // no further barriers
    if (cnt_all == 0) return;
    const int cnt = cnt_all;

    // ---- in-wave stable rank sort by key desc (two keys per lane) ----
    {
        unsigned long long Ka = (l < cnt) ? mk[l] : 0ull;
        unsigned long long Kb = (64 + l < cnt) ? mk[64 + l] : 0ull;
        int ra = 0, rb = 0;
        for (int t = 0; t < cnt; ++t) {
            unsigned long long kt = mk[t];           // uniform LDS broadcast
            ra += (kt > Ka);
            rb += (kt > Kb);
        }
        if (l < cnt) mk[ra] = Ka;
        if (64 + l < cnt) mk[rb] = Kb;
    }

    // fetch member boxes (sorted order)
    for (int t = l; t < cnt; t += 64) {
        int i = (int)(~(unsigned int)mk[t]);
        mbox[t] = bxs[i];
    }

    // ---- chunk 0: ballot fixpoint == greedy (validated exact) ----
    unsigned long long kept0 = 0ull;
    {
        bool act = (l < cnt);
        float4 a = mbox[act ? l : 0];
        float aarea = (a.z - a.x) * (a.w - a.y);
        unsigned long long colmask = 0ull;
        int tend = min(64, cnt);
        for (int t = 0; t < tend; ++t) {
            float4 tb = mbox[t];                     // uniform LDS broadcast
            if (t < l && act && iou_gt_thr(a, aarea, tb)) colmask |= (1ull << t);
        }
        unsigned long long kept = __ballot(act);
        while (true) {
            bool alive = act && ((colmask & kept) == 0ull);
            unsigned long long k2m = __ballot(alive);
            if (k2m == kept) break;
            kept = k2m;
        }
        kept0 = kept;
        bool alive = act && ((colmask & kept0) == 0ull);
        if (alive) kflag[(size_t)b * NN + (int)(~(unsigned int)mk[l])] = 1;
    }
    // ---- chunk 1 (members 64..cnt-1): rare ----
    if (cnt > 64) {
        int m = 64 + l;
        bool act = (m < cnt);
        float4 a = mbox[act ? m : 0];
        float aarea = (a.z - a.x) * (a.w - a.y);
        bool presup = false;
        for (int t = 0; t < 64; ++t) {
            if ((kept0 >> t) & 1ull) {
                if (act && iou_gt_thr(a, aarea, mbox[t])) presup = true;
            }
        }
        unsigned long long colmask = 0ull;
        for (int t = 64; t < cnt; ++t) {
            float4 tb = mbox[t];
            if ((t - 64) < l && act && iou_gt_thr(a, aarea, tb)) colmask |= (1ull << (t - 64));
        }
        bool pre = act && !presup;
        unsigned long long kept = __ballot(pre);
        while (true) {
            bool alive = pre && ((colmask & kept) == 0ull);
            unsigned long long k2m = __ballot(alive);
            if (k2m == kept) break;
            kept = k2m;
        }
        bool alive = pre && ((colmask & kept) == 0ull);
        if (alive) kflag[(size_t)b * NN + (int)(~(unsigned int)mk[64 + l])] = 1;
    }
}

// ---- kC: 1 block per batch x 1024 threads. Positional key build (no slots,
// no prefix, no scatter): keys[i] = kflag[i] ? mkey : 0, coalesced, 2 iters.
// Then histogram threshold (validated) + candidate rank-count + write. ----
__global__ void __launch_bounds__(1024) kC_emit(
        const int* __restrict__ kflag,
        const float* __restrict__ sc,
        const float* __restrict__ boxes,
        const int* __restrict__ cls,
        float* __restrict__ out) {
    const int b = blockIdx.x;
    const int tid = threadIdx.x;
    const int wv = tid >> 6;
    const int l = tid & 63;

    __shared__ unsigned long long keys[2048];        // 16 KB (keys[i] by row)
    __shared__ ulonglong2 cand2[256];                //  4 KB
    __shared__ int hist[256];
    __shared__ int Tcnt, tbsh, candn;
    unsigned long long* cand = (unsigned long long*)cand2;

    if (tid < 256) hist[tid] = 0;
    if (tid < 48) keys[2000 + tid] = 0ull;           // pad tail
    if (tid == 0) { Tcnt = 0; candn = 0; }
    __syncthreads();

    // build keys positionally + histogram + count (2 coalesced iterations)
    for (int i = tid; i < NN; i += 1024) {
        int f = kflag[(size_t)b * NN + i];
        unsigned long long k = f ? mkey(sc[(size_t)b * NN + i], i) : 0ull;
        keys[i] = k;
        if (f) atomicAdd(&hist[(int)((k >> 47) & 0xFF)], 1);
        unsigned long long m = __ballot(f != 0);
        if (l == 0 && m) atomicAdd(&Tcnt, __popcll(m));
    }
    __syncthreads();
    const int T = Tcnt;
    if (T == 0) return;                              // out pre-zeroed by kA

    // wave 0: threshold bucket tb (smallest b' with count(buckets >= b') >= 100)
    // (scores in [0.7,1) -> exponent fixed -> bucket (key>>47)&0xFF monotone)
    if (wv == 0) {
        int cum = 0, tb = 0, done = 0;
        for (int chunk = 3; chunk >= 0 && !done; --chunk) {
            int bkt = chunk * 64 + (63 - l);         // lane 0 = highest bucket
            int s = hist[bkt];
            #pragma unroll
            for (int off = 1; off < 64; off <<= 1) {
                int o = __shfl_up(s, off);
                if (l >= off) s += o;
            }
            int chunktot = __shfl(s, 63);
            if (cum + chunktot >= MAXI) {
                unsigned long long m = __ballot(cum + s >= MAXI);
                int lane = __ffsll((long long)m) - 1;
                tb = chunk * 64 + (63 - lane);
                done = 1;
            } else {
                cum += chunktot;
            }
        }
        if (l == 0) tbsh = done ? tb : 0;            // T<100 -> all buckets
    }
    __syncthreads();
    const int tb = tbsh;

    // compact candidates (bucket >= tb); non-candidates have strictly smaller
    // keys, so rank among candidates == global rank. Order in cand[] irrelevant.
    for (int i = tid; i < NN; i += 1024) {
        unsigned long long k = keys[i];
        bool pr = (k != 0ull) && ((int)((k >> 47) & 0xFF) >= tb);
        unsigned long long m = __ballot(pr);
        int basew = 0;
        if (l == 0 && m) basew = atomicAdd(&candn, __popcll(m));
        basew = __shfl(basew, 0);
        if (pr) {
            int pos = basew + __popcll(m & ((1ull << l) - 1ull));
            if (pos < 512) cand[pos] = k;
        }
    }
    __syncthreads();
    const int nc = candn;
    if (tid == 0 && nc < 512) cand[nc] = 0ull;       // pad for pair read
    __syncthreads();

    if (nc <= 512) {
        // rank-count among candidates (~53 uniform pair reads for nc~106)
        const int np = (nc + 1) >> 1;
        for (int s = tid; s < nc; s += 1024) {
            unsigned long long myk = cand[s];
            int r = 0;
            for (int t = 0; t < np; ++t) {
                ulonglong2 kv = cand2[t];
                r += (int)(kv.x > myk);
                r += (int)(kv.y > myk);              // pad 0 never counts
            }
            if (r < MAXI) {
                int i = (int)(~(unsigned int)myk);
                float4 bx = ((const float4*)boxes)[(size_t)b * NN + i];
                float* o = out + ((size_t)b * MAXI + r) * 6;
                o[0] = bx.x; o[1] = bx.y; o[2] = bx.z; o[3] = bx.w;
                o[4] = (float)cls[(size_t)b * NN + i];
                o[5] = __uint_as_float((unsigned int)(myk >> 32));
            }
        }
    } else {
        // pathological fallback: rank over all rows (keys[i]==0 excluded)
        for (int s = tid; s < NN; s += 1024) {
            unsigned long long myk = keys[s];
            if (myk == 0ull) continue;
            int r = 0;
            for (int t = 0; t < 1024; ++t) {
                ulonglong2 kv = ((ulonglong2*)keys)[t];
                r += (int)(kv.x > myk);
                r += (int)(kv.y > myk);
            }
            if (r < MAXI) {
                int i = (int)(~(unsigned int)myk);
                float4 bx = ((const float4*)boxes)[(size_t)b * NN + i];
                float* o = out + ((size_t)b * MAXI + r) * 6;
                o[0] = bx.x; o[1] = bx.y; o[2] = bx.z; o[3] = bx.w;
                o[4] = (float)cls[(size_t)b * NN + i];
                o[5] = __uint_as_float((unsigned int)(myk >> 32));
            }
        }
    }
}

extern "C" void kernel_launch(void* const* d_in, const int* in_sizes, int n_in,
                              void* d_out, int out_size, void* d_ws, size_t ws_size,
                              hipStream_t stream) {
    const float* rois   = (const float*)d_in[0];
    const float* probs  = (const float*)d_in[1];
    const float* deltas = (const float*)d_in[2];
    float* outp = (float*)d_out;

    char* ws = (char*)d_ws;
    float* boxes = (float*)(ws + 0);
    float* sc    = (float*)(ws + 256000);
    int*   cls   = (int*)  (ws + 320000);
    int*   kflag = (int*)  (ws + 384000);

    {
        int blocks = (BB * NN * 64) / 256;   // one wave per ROI, exact
        kA_refine<<<blocks, 256, 0, stream>>>(rois, probs, deltas, boxes, sc, cls, kflag, outp);
    }
    {
        kB_nms<<<BB * NCLS, 256, 0, stream>>>(boxes, sc, cls, kflag);
    }
    {
        kC_emit<<<BB, 1024, 0, stream>>>(kflag, sc, boxes, cls, outp);
    }
}